// Round 3
// baseline (191.553 us; speedup 1.0000x reference)
//
#include <hip/hip_runtime.h>
#include <hip/hip_bf16.h>

// Problem constants (from setup_inputs)
#define Bb 8
#define Tt 20
#define Nn 16
#define Cc 1024
#define ROWS (Bb * Tt * Nn)   // 2560
#define K2 9

typedef __attribute__((ext_vector_type(8))) short short8;
typedef __attribute__((ext_vector_type(8))) _Float16 half8;
typedef __attribute__((ext_vector_type(4))) _Float16 half4;
typedef __attribute__((ext_vector_type(4))) float floatx4;
typedef __attribute__((address_space(1))) const unsigned int guint;
typedef __attribute__((address_space(3))) unsigned int luint;

static __device__ __forceinline__ unsigned short f2bf(float f) {
    unsigned int u = __builtin_bit_cast(unsigned int, f);
    unsigned int lsb = (u >> 16) & 1u;
    u += 0x7fffu + lsb;                 // round-to-nearest-even
    return (unsigned short)(u >> 16);
}

// ---------------------------------------------------------------------------
// Kernel 0 (prep): one kernel, three block-segments.
//   [0,1024)      : W_hidden fp32 -> bf16 (4 elem/thread)
//   [1024,3584)   : x fp32 -> fp16        (4 elem/thread)
//   [3584,4736)   : conv weights -> [tap][32][C] fp16 (o zero-padded to 32)
// (off init + zero page dropped: offs kernel now writes off directly.)
// ---------------------------------------------------------------------------
#define SEG0 1024
#define SEG1 3584
#define SEG2 4736

__global__ __launch_bounds__(256) void prep_kernel(const float* __restrict__ pf,
                                                   const float* __restrict__ Wh,
                                                   const float* __restrict__ w1,
                                                   const float* __restrict__ w2,
                                                   unsigned short* __restrict__ Wb,
                                                   _Float16* __restrict__ xh,
                                                   _Float16* __restrict__ wh1,
                                                   _Float16* __restrict__ wh2) {
    const int bid = blockIdx.x;
    const int tid = threadIdx.x;
    if (bid < SEG0) {
        int idx = (bid * 256 + tid) * 4;
        float4 v = *(const float4*)(Wh + idx);
        ushort4 o;
        o.x = f2bf(v.x); o.y = f2bf(v.y); o.z = f2bf(v.z); o.w = f2bf(v.w);
        *(ushort4*)(Wb + idx) = o;
    } else if (bid < SEG1) {
        int idx = ((bid - SEG0) * 256 + tid) * 4;
        float4 v = *(const float4*)(pf + idx);
        half4 o;
        o.x = (_Float16)v.x; o.y = (_Float16)v.y; o.z = (_Float16)v.z; o.w = (_Float16)v.w;
        *(half4*)(xh + idx) = o;
    } else {
        int idx = (bid - SEG1) * 256 + tid;     // 9*32*1024 total
        int c = idx & 1023;
        int o = (idx >> 10) & 31;
        int tap = idx >> 15;
        float v1 = 0.f, v2 = 0.f;
        if (o < 18) {
            size_t src = ((size_t)o * Cc + c) * 9 + tap;
            v1 = w1[src]; v2 = w2[src];
        }
        wh1[idx] = (_Float16)v1;
        wh2[idx] = (_Float16)v2;
    }
}

// ---------------------------------------------------------------------------
// Kernel 1 (REWRITTEN): offset conv, ALL 9 taps per block.
// Grid (40 M-tiles of 64 rows, 2 ratios) = 80 blocks, 4 waves.
// A window (tile rows +-34, padded to 144 + zero-row) staged ONCE per K-step
// and shared by all taps (was re-staged 18x before); B = all 9 taps' weights.
// BK=32 double-buffered (55 KB LDS), ONE barrier per K-step, 18 MFMAs per
// wave per barrier-pair (was 4). Each block owns its 64 rows x 18 outputs
// for its ratio -> direct stores + bias, NO atomics, NO off init.
// Tap validity: each wave's 16 rows span one t-slice, so t-validity is
// wave-uniform; n-validity is l15+dn in [0,16). Invalid (row,tap) pairs
// read a zeroed LDS row (144) via precomputed per-lane addresses.
// ---------------------------------------------------------------------------
__global__ __launch_bounds__(256) void offs_mfma_kernel(const _Float16* __restrict__ xh,
                                                        const _Float16* __restrict__ wh1,
                                                        const _Float16* __restrict__ wh2,
                                                        const float* __restrict__ b1,
                                                        const float* __restrict__ b2,
                                                        float* __restrict__ off1,
                                                        float* __restrict__ off2) {
    __shared__ unsigned short As[2][146 * 32];      // 2 x 9.1 KB (rows: 144 win + zero + pad)
    __shared__ unsigned short Bs[2][9 * 32 * 32];   // 2 x 18 KB

    const int tid  = threadIdx.x;
    const int lane = tid & 63;
    const int wave = tid >> 6;
    const int quad = lane >> 4;
    const int l15  = lane & 15;
    const int row0 = blockIdx.x * 64;               // 64 | 320: never crosses a batch
    const int ratio = blockIdx.y + 1;
    const _Float16* __restrict__ wh = blockIdx.y ? wh2 : wh1;
    const float* __restrict__ bias  = blockIdx.y ? b2 : b1;
    float* __restrict__ off         = blockIdx.y ? off2 : off1;

    const int wrow = wave * 16;                     // this wave's 16 rows = one t-slice
    const int t_w  = ((row0 + wrow) >> 4) % Tt;

    // ---- staging source offsets (elements), swizzle: pos p holds chunk p^(row&3)
    // B: 18 chunk-groups of 64 (9 taps x 32 rows x 4 chunks); A: 9 groups (144 rows x 4).
    unsigned bOffs[5], aOffs[3];
#pragma unroll
    for (int i = 0; i < 5; ++i) {
        const int c = (wave + i * 4) * 64 + lane;
        const int tap = c >> 7, rem = c & 127, o = rem >> 2, p = rem & 3;
        bOffs[i] = tap * 32768 + o * 1024 + ((p ^ (o & 3)) << 3);
    }
#pragma unroll
    for (int i = 0; i < 3; ++i) {
        const int c = (wave + i * 4) * 64 + lane;
        const int r = c >> 2, p = c & 3;
        int gr = row0 - 40 + r;                     // clamp for safety; invalid rows
        gr = gr < 0 ? 0 : (gr > ROWS - 1 ? ROWS - 1 : gr);  // are masked by validity
        aOffs[i] = (unsigned)gr * 1024 + ((p ^ (r & 3)) << 3);
    }

    auto stage = [&](int buf, int kt) {
#pragma unroll
        for (int i = 0; i < 5; ++i) {
            const int g = wave + i * 4;
            if (g < 18)
                __builtin_amdgcn_global_load_lds((guint*)(const void*)(wh + bOffs[i] + kt),
                                                 (luint*)(void*)&Bs[buf][g * 512], 16, 0, 0);
        }
#pragma unroll
        for (int i = 0; i < 3; ++i) {
            const int g = wave + i * 4;
            if (g < 9)
                __builtin_amdgcn_global_load_lds((guint*)(const void*)(xh + aOffs[i] + kt),
                                                 (luint*)(void*)&As[buf][g * 512], 16, 0, 0);
        }
    };

    // ---- per-tap A read addresses (shorts within one As buffer), constant over K
    int addrA[9];
#pragma unroll
    for (int tap = 0; tap < 9; ++tap) {
        const int dt = (tap / 3 - 1) * ratio;
        const int dn = (tap % 3 - 1) * ratio;
        const bool tv = (unsigned)(t_w + dt) < (unsigned)Tt;   // wave-uniform
        const bool nv = (unsigned)(l15 + dn) < (unsigned)Nn;   // per-lane
        const int r  = wrow + l15 + 40 + dt * 16 + dn;         // window row
        const int rr = (tv && nv) ? r : 144;                   // else zero row
        addrA[tap] = rr * 32 + ((quad ^ (rr & 3)) << 3);
    }
    const int bOff0 = l15 * 32 + ((quad ^ (l15 & 3)) << 3);

    // zero row 144 in both buffers (staging never touches rows >= 144)
    if (tid < 8) {
        short8 z = {0, 0, 0, 0, 0, 0, 0, 0};
        *(short8*)&As[tid >> 2][144 * 32 + (tid & 3) * 8] = z;
    }

    floatx4 acc[2];
    acc[0] = (floatx4){0.f, 0.f, 0.f, 0.f};
    acc[1] = (floatx4){0.f, 0.f, 0.f, 0.f};

    stage(0, 0);
    __syncthreads();
    int cur = 0;
    for (int kt = 0; kt < Cc; kt += 32) {
        const bool more = (kt + 32 < Cc);
        if (more) stage(cur ^ 1, kt + 32);          // prefetch under the MFMAs
#pragma unroll
        for (int tap = 0; tap < 9; ++tap) {
            const half8 av  = __builtin_bit_cast(half8, *(const short8*)&As[cur][addrA[tap]]);
            const half8 bv0 = __builtin_bit_cast(half8, *(const short8*)&Bs[cur][tap * 1024 + bOff0]);
            const half8 bv1 = __builtin_bit_cast(half8, *(const short8*)&Bs[cur][tap * 1024 + 512 + bOff0]);
            acc[0] = __builtin_amdgcn_mfma_f32_16x16x32_f16(av, bv0, acc[0], 0, 0, 0);
            acc[1] = __builtin_amdgcn_mfma_f32_16x16x32_f16(av, bv1, acc[1], 0, 0, 0);
        }
        if (more) __syncthreads();                  // single drain point per K-step
        cur ^= 1;
    }

    // each block exclusively owns rows [row0, row0+64) x 18 outputs: direct store
#pragma unroll
    for (int j = 0; j < 2; ++j) {
        const int o = j * 16 + l15;
        if (o < 18) {
            const float bo = bias[o];
            const int grow = row0 + wrow + quad * 4;
#pragma unroll
            for (int r = 0; r < 4; ++r)
                off[(size_t)(grow + r) * 18 + o] = acc[j][r] + bo;
        }
    }
}

// ---------------------------------------------------------------------------
// Kernel 2: fused deformable bilinear gather, descriptor form (round-1 known-
// good config: fp32 pf reads, bijective XCD swizzle, nontemporal mad stores).
// ---------------------------------------------------------------------------
__global__ __launch_bounds__(256) void gather_kernel(const float* __restrict__ pf,
                                                     const float* __restrict__ off1,
                                                     const float* __restrict__ off2,
                                                     unsigned short* __restrict__ Ab,
                                                     float* __restrict__ mad) {
    const int bid = blockIdx.x;
    const int row = (bid & 7) * (ROWS / 8) + (bid >> 3);   // bijective XCD swizzle
    const int b = row / (Tt * Nn);
    const int t = (row / Nn) % Tt;
    const int n = row % Nn;
    const int tid = threadIdx.x;

    __shared__ float4 scoef[18];
    __shared__ int4   soffs[18];

    if (tid < 18) {
        const int ratio = (tid < 9) ? 1 : 2;
        const int k = (tid < 9) ? tid : tid - 9;
        const float* offarr = (tid < 9) ? off1 : off2;
        const float ot = offarr[(size_t)row * 18 + k];
        const float on = offarr[(size_t)row * 18 + 9 + k];
        const float tmax = (float)(Tt + 2 * ratio - 1);
        const float nmax = (float)(Nn + 2 * ratio - 1);
        const float pos_t = (float)(t + ratio + (k / 3 - 1) * ratio) + ot;
        const float pos_n = (float)(n + ratio + (k % 3 - 1) * ratio) + on;

        const float fl_t = floorf(pos_t), fl_n = floorf(pos_n);
        const float l_t = fminf(fmaxf(fl_t, 0.f), tmax);
        const float r_t = fminf(fmaxf(fl_t + 1.f, 0.f), tmax);
        const float l_n = fminf(fmaxf(fl_n, 0.f), nmax);
        const float r_n = fminf(fmaxf(fl_n + 1.f, 0.f), nmax);
        const float pt_ = fminf(fmaxf(pos_t, 0.f), tmax);
        const float pn_ = fminf(fmaxf(pos_n, 0.f), nmax);

        const float wtl = 1.f - fabsf(pt_ - l_t);
        const float wtr = 1.f - fabsf(pt_ - r_t);
        const float wnl = 1.f - fabsf(pn_ - l_n);
        const float wnr = 1.f - fabsf(pn_ - r_n);

        const int ilt = (int)l_t - ratio, irt = (int)r_t - ratio;
        const int iln = (int)l_n - ratio, irn = (int)r_n - ratio;
        const bool vtl = (unsigned)ilt < (unsigned)Tt;
        const bool vtr = (unsigned)irt < (unsigned)Tt;
        const bool vnl = (unsigned)iln < (unsigned)Nn;
        const bool vnr = (unsigned)irn < (unsigned)Nn;

        const int bb = b * Tt;
        float4 cf;
        int4 of;
        const bool g0 = vtl && vnl, g1 = vtr && vnr, g2 = vtr && vnl, g3 = vtl && vnr;
        cf.x = g0 ? wtl * wnl : 0.f;
        cf.y = g1 ? wtr * wnr : 0.f;
        cf.z = g2 ? wtr * wnl : 0.f;
        cf.w = g3 ? wtl * wnr : 0.f;
        of.x = g0 ? ((bb + ilt) * Nn + iln) * Cc : 0;
        of.y = g1 ? ((bb + irt) * Nn + irn) * Cc : 0;
        of.z = g2 ? ((bb + irt) * Nn + iln) * Cc : 0;
        of.w = g3 ? ((bb + ilt) * Nn + irn) * Cc : 0;
        scoef[tid] = cf;
        soffs[tid] = of;
    }
    __syncthreads();

    const int c4 = tid * 4;
    float ax = 0.f, ay = 0.f, az = 0.f, aw = 0.f;

#pragma unroll
    for (int d = 0; d < 9; ++d) {
        const float4 cf = scoef[d];
        const int4 of = soffs[d];
        const float4 v0 = *(const float4*)(pf + of.x + c4);
        const float4 v1 = *(const float4*)(pf + of.y + c4);
        const float4 v2 = *(const float4*)(pf + of.z + c4);
        const float4 v3 = *(const float4*)(pf + of.w + c4);
        ax += cf.x * v0.x + cf.y * v1.x + cf.z * v2.x + cf.w * v3.x;
        ay += cf.x * v0.y + cf.y * v1.y + cf.z * v2.y + cf.w * v3.y;
        az += cf.x * v0.z + cf.y * v1.z + cf.z * v2.z + cf.w * v3.z;
        aw += cf.x * v0.w + cf.y * v1.w + cf.z * v2.w + cf.w * v3.w;
    }
#pragma unroll
    for (int d = 9; d < 18; ++d) {
        const float4 cf = scoef[d];
        const int4 of = soffs[d];
        const float4 v0 = *(const float4*)(pf + of.x + c4);
        const float4 v1 = *(const float4*)(pf + of.y + c4);
        const float4 v2 = *(const float4*)(pf + of.z + c4);
        const float4 v3 = *(const float4*)(pf + of.w + c4);
        floatx4 val;
        val.x = cf.x * v0.x + cf.y * v1.x + cf.z * v2.x + cf.w * v3.x;
        val.y = cf.x * v0.y + cf.y * v1.y + cf.z * v2.y + cf.w * v3.y;
        val.z = cf.x * v0.z + cf.y * v1.z + cf.z * v2.z + cf.w * v3.z;
        val.w = cf.x * v0.w + cf.y * v1.w + cf.z * v2.w + cf.w * v3.w;
        __builtin_nontemporal_store(val,
            (floatx4*)(mad + ((size_t)row * 9 + (d - 9)) * Cc + c4));
        ax += val.x; ay += val.y; az += val.z; aw += val.w;
    }

    ushort4 o;
    o.x = f2bf(ax * (1.f / 18.f));
    o.y = f2bf(ay * (1.f / 18.f));
    o.z = f2bf(az * (1.f / 18.f));
    o.w = f2bf(aw * (1.f / 18.f));
    *(ushort4*)(Ab + (size_t)row * Cc + c4) = o;
}

// ---------------------------------------------------------------------------
// Kernel 3: bf16 MFMA GEMM  C[M][N] = A[M][K] * B[N][K]^T, 64x64 tiles
// (grid 40x16 = 640 blocks — round-1 known-good config). 4 waves, each 32x32.
// BK=64 double-buffered, single barrier per K-step. Nontemporal C stores.
// ---------------------------------------------------------------------------
__global__ __launch_bounds__(256) void gemm_bt_kernel(const unsigned short* __restrict__ A,
                                                      const unsigned short* __restrict__ Bw,
                                                      float* __restrict__ C,
                                                      int M, int N, int K) {
    __shared__ unsigned short As[2][64 * 64];   // 2 x 8 KB
    __shared__ unsigned short Bs[2][64 * 64];   // 2 x 8 KB

    const int tid  = threadIdx.x;
    const int lane = tid & 63;
    const int wave = tid >> 6;
    const int quad = lane >> 4;
    const int l15  = lane & 15;
    const int row0 = blockIdx.x * 64;
    const int col0 = blockIdx.y * 64;
    const int wm = (wave >> 1) * 32;
    const int wn = (wave & 1) * 32;

    floatx4 acc[2][2];
#pragma unroll
    for (int i = 0; i < 2; ++i)
#pragma unroll
        for (int j = 0; j < 2; ++j) acc[i][j] = (floatx4){0.f, 0.f, 0.f, 0.f};

    const int p  = tid & 7;
    const int m0 = tid >> 3;
    const int m1 = m0 + 32;
    const int kq0 = p ^ (m0 & 7);
    const int kq1 = p ^ (m1 & 7);

    const unsigned short* gA0 = A  + (size_t)(row0 + m0) * K + kq0 * 8;
    const unsigned short* gA1 = A  + (size_t)(row0 + m1) * K + kq1 * 8;
    const unsigned short* gB0 = Bw + (size_t)(col0 + m0) * K + kq0 * 8;
    const unsigned short* gB1 = Bw + (size_t)(col0 + m1) * K + kq1 * 8;

    auto stage = [&](int buf, int kt) {
        unsigned short* a  = &As[buf][0] + wave * 512;
        unsigned short* bb = &Bs[buf][0] + wave * 512;
        __builtin_amdgcn_global_load_lds((guint*)(const void*)(gA0 + kt),
                                         (luint*)(void*)a, 16, 0, 0);
        __builtin_amdgcn_global_load_lds((guint*)(const void*)(gA1 + kt),
                                         (luint*)(void*)(a + 2048), 16, 0, 0);
        __builtin_amdgcn_global_load_lds((guint*)(const void*)(gB0 + kt),
                                         (luint*)(void*)bb, 16, 0, 0);
        __builtin_amdgcn_global_load_lds((guint*)(const void*)(gB1 + kt),
                                         (luint*)(void*)(bb + 2048), 16, 0, 0);
    };

    stage(0, 0);
    __syncthreads();
    int cur = 0;
    for (int kt = 0; kt < K; kt += 64) {
        const bool more = (kt + 64 < K);
        if (more) stage(cur ^ 1, kt + 64);   // prefetch under the MFMAs

#pragma unroll
        for (int kt2 = 0; kt2 < 2; ++kt2) {
            short8 af[2], bf[2];
#pragma unroll
            for (int i = 0; i < 2; ++i) {
                const int mm = wm + i * 16 + l15;
                af[i] = *(const short8*)&As[cur][mm * 64 + (((kt2 * 4 + quad) ^ (mm & 7)) << 3)];
                const int nn = wn + i * 16 + l15;
                bf[i] = *(const short8*)&Bs[cur][nn * 64 + (((kt2 * 4 + quad) ^ (nn & 7)) << 3)];
            }
#pragma unroll
            for (int i = 0; i < 2; ++i)
#pragma unroll
                for (int j = 0; j < 2; ++j)
                    acc[i][j] = __builtin_amdgcn_mfma_f32_16x16x32_bf16(af[i], bf[j], acc[i][j], 0, 0, 0);
        }
        if (more) __syncthreads();
        cur ^= 1;
    }

#pragma unroll
    for (int i = 0; i < 2; ++i)
#pragma unroll
        for (int j = 0; j < 2; ++j)
#pragma unroll
            for (int r = 0; r < 4; ++r) {
                const int row = row0 + wm + i * 16 + quad * 4 + r;
                const int col = col0 + wn + j * 16 + l15;
                __builtin_nontemporal_store(acc[i][j][r], &C[(size_t)row * N + col]);
            }
}

// ---------------------------------------------------------------------------
extern "C" void kernel_launch(void* const* d_in, const int* in_sizes, int n_in,
                              void* d_out, int out_size, void* d_ws, size_t ws_size,
                              hipStream_t stream) {
    const float* pf = (const float*)d_in[0];   // [B,T,N,C]
    const float* Wh = (const float*)d_in[1];   // [C,C]
    const float* w1 = (const float*)d_in[2];   // [18,C,3,3]
    const float* b1 = (const float*)d_in[3];   // [18]
    const float* w2 = (const float*)d_in[4];
    const float* b2 = (const float*)d_in[5];

    float* dyn = (float*)d_out;                    // [ROWS][C]
    float* mad = dyn + (size_t)ROWS * Cc;          // [ROWS][9][C]

    // workspace layout
    float* off1  = (float*)d_ws;                                  // ROWS*18
    float* off2  = off1 + (size_t)ROWS * 18;                      // ROWS*18
    unsigned short* Ab = (unsigned short*)(off2 + (size_t)ROWS * 18);    // ROWS*C bf16
    unsigned short* Wb = Ab + (size_t)ROWS * Cc;                  // C*C bf16
    _Float16* xh  = (_Float16*)(Wb + (size_t)Cc * Cc);            // ROWS*C fp16
    _Float16* wh1 = xh + (size_t)ROWS * Cc;                       // 9*32*C fp16
    _Float16* wh2 = wh1 + (size_t)9 * 32 * Cc;                    // 9*32*C fp16

    prep_kernel<<<SEG2, 256, 0, stream>>>(pf, Wh, w1, w2, Wb, xh, wh1, wh2);
    offs_mfma_kernel<<<dim3(ROWS / 64, 2), 256, 0, stream>>>(xh, wh1, wh2, b1, b2, off1, off2);
    gather_kernel<<<ROWS, 256, 0, stream>>>(pf, off1, off2, Ab, mad);
    gemm_bt_kernel<<<dim3(40, 16), 256, 0, stream>>>(Ab, Wb, dyn, ROWS, Cc, Cc);
}

// Round 4
// 172.806 us; speedup vs baseline: 1.1085x; 1.1085x over previous
//
#include <hip/hip_runtime.h>
#include <hip/hip_bf16.h>

// Problem constants (from setup_inputs)
#define Bb 8
#define Tt 20
#define Nn 16
#define Cc 1024
#define ROWS (Bb * Tt * Nn)   // 2560
#define K2 9

typedef __attribute__((ext_vector_type(8))) short short8;
typedef __attribute__((ext_vector_type(8))) _Float16 half8;
typedef __attribute__((ext_vector_type(4))) _Float16 half4;
typedef __attribute__((ext_vector_type(4))) float floatx4;
typedef __attribute__((address_space(1))) const unsigned int guint;
typedef __attribute__((address_space(3))) unsigned int luint;

static __device__ __forceinline__ unsigned short f2bf(float f) {
    unsigned int u = __builtin_bit_cast(unsigned int, f);
    unsigned int lsb = (u >> 16) & 1u;
    u += 0x7fffu + lsb;                 // round-to-nearest-even
    return (unsigned short)(u >> 16);
}

// ---------------------------------------------------------------------------
// Kernel 0 (prep): one kernel, four block-segments.
//   [0,1024)      : W_hidden fp32 -> bf16 (4 elem/thread)
//   [1024,3584)   : x fp32 -> fp16        (4 elem/thread)
//   [3584,4736)   : conv weights -> [tap][32][C] fp16 (o zero-padded to 32)
//   [4736,4916)   : off1/off2 bias init (offs kernel atomicAdds partials)
// ---------------------------------------------------------------------------
#define SEG0 1024
#define SEG1 3584
#define SEG2 4736
#define SEG3 4916

__global__ __launch_bounds__(256) void prep_kernel(const float* __restrict__ pf,
                                                   const float* __restrict__ Wh,
                                                   const float* __restrict__ w1,
                                                   const float* __restrict__ b1,
                                                   const float* __restrict__ w2,
                                                   const float* __restrict__ b2,
                                                   unsigned short* __restrict__ Wb,
                                                   _Float16* __restrict__ xh,
                                                   _Float16* __restrict__ wh1,
                                                   _Float16* __restrict__ wh2,
                                                   float* __restrict__ off1,
                                                   float* __restrict__ off2) {
    const int bid = blockIdx.x;
    const int tid = threadIdx.x;
    if (bid < SEG0) {
        int idx = (bid * 256 + tid) * 4;
        float4 v = *(const float4*)(Wh + idx);
        ushort4 o;
        o.x = f2bf(v.x); o.y = f2bf(v.y); o.z = f2bf(v.z); o.w = f2bf(v.w);
        *(ushort4*)(Wb + idx) = o;
    } else if (bid < SEG1) {
        int idx = ((bid - SEG0) * 256 + tid) * 4;
        float4 v = *(const float4*)(pf + idx);
        half4 o;
        o.x = (_Float16)v.x; o.y = (_Float16)v.y; o.z = (_Float16)v.z; o.w = (_Float16)v.w;
        *(half4*)(xh + idx) = o;
    } else if (bid < SEG2) {
        int idx = (bid - SEG1) * 256 + tid;     // 9*32*1024 total
        int c = idx & 1023;
        int o = (idx >> 10) & 31;
        int tap = idx >> 15;
        float v1 = 0.f, v2 = 0.f;
        if (o < 18) {
            size_t src = ((size_t)o * Cc + c) * 9 + tap;
            v1 = w1[src]; v2 = w2[src];
        }
        wh1[idx] = (_Float16)v1;
        wh2[idx] = (_Float16)v2;
    } else {
        int idx = (bid - SEG2) * 256 + tid;     // ROWS*18 = 46080 = 180*256
        int o = idx % 18;
        off1[idx] = b1[o];
        off2[idx] = b2[o];
    }
}

// ---------------------------------------------------------------------------
// Kernel 1: offset conv, ALL 9 taps per block, K-SPLIT for parallelism.
// Grid (40 M-tiles of 64 rows, 8 K-chunks of 128, 2 ratios) = 640 blocks
// (2.5 blocks/CU issued; 55 KB LDS -> 2 co-resident/CU — R3's failure was
// 80 blocks = 0.3/CU, no TLP to hide the barrier drain).
// Per block: A window (tile rows +-34 -> 144 rows + LDS zero-row) staged
// ONCE per K-step and shared by all 9 taps; B = all 9 taps' weights.
// BK=32 double-buffered, ONE barrier per K-step, 18 MFMAs per wave per
// barrier-pair. Partial K-sums atomicAdd'ed into bias-initialized off.
// Tap validity: each wave's 16 rows span one t-slice, so t-validity is
// wave-uniform; n-validity is l15+dn in [0,16). Invalid (row,tap) pairs
// read the zeroed LDS row (144) via precomputed per-lane addresses.
// ---------------------------------------------------------------------------
__global__ __launch_bounds__(256) void offs_mfma_kernel(const _Float16* __restrict__ xh,
                                                        const _Float16* __restrict__ wh1,
                                                        const _Float16* __restrict__ wh2,
                                                        float* __restrict__ off1,
                                                        float* __restrict__ off2) {
    __shared__ unsigned short As[2][146 * 32];      // 2 x 9.1 KB (144 win + zero + pad)
    __shared__ unsigned short Bs[2][9 * 32 * 32];   // 2 x 18 KB

    const int tid  = threadIdx.x;
    const int lane = tid & 63;
    const int wave = tid >> 6;
    const int quad = lane >> 4;
    const int l15  = lane & 15;
    const int row0 = blockIdx.x * 64;               // 64 | 320: never crosses a batch
    const int kc   = blockIdx.y * 128;              // this block's K range: [kc, kc+128)
    const int ratio = blockIdx.z + 1;
    const _Float16* __restrict__ wh = blockIdx.z ? wh2 : wh1;
    float* __restrict__ off         = blockIdx.z ? off2 : off1;

    const int wrow = wave * 16;                     // this wave's 16 rows = one t-slice
    const int t_w  = ((row0 + wrow) >> 4) % Tt;

    // ---- staging source offsets (elements), swizzle: pos p holds chunk p^(row&3)
    // B: 18 chunk-groups of 64 (9 taps x 32 rows x 4 chunks); A: 9 groups (144 rows x 4).
    unsigned bOffs[5], aOffs[3];
#pragma unroll
    for (int i = 0; i < 5; ++i) {
        const int c = (wave + i * 4) * 64 + lane;
        const int tap = c >> 7, rem = c & 127, o = rem >> 2, p = rem & 3;
        bOffs[i] = tap * 32768 + o * 1024 + ((p ^ (o & 3)) << 3);
    }
#pragma unroll
    for (int i = 0; i < 3; ++i) {
        const int c = (wave + i * 4) * 64 + lane;
        const int r = c >> 2, p = c & 3;
        int gr = row0 - 40 + r;                     // clamp for safety; invalid rows
        gr = gr < 0 ? 0 : (gr > ROWS - 1 ? ROWS - 1 : gr);  // are masked by validity
        aOffs[i] = (unsigned)gr * 1024 + ((p ^ (r & 3)) << 3);
    }

    auto stage = [&](int buf, int kt) {
#pragma unroll
        for (int i = 0; i < 5; ++i) {
            const int g = wave + i * 4;
            if (g < 18)
                __builtin_amdgcn_global_load_lds((guint*)(const void*)(wh + bOffs[i] + kt),
                                                 (luint*)(void*)&Bs[buf][g * 512], 16, 0, 0);
        }
#pragma unroll
        for (int i = 0; i < 3; ++i) {
            const int g = wave + i * 4;
            if (g < 9)
                __builtin_amdgcn_global_load_lds((guint*)(const void*)(xh + aOffs[i] + kt),
                                                 (luint*)(void*)&As[buf][g * 512], 16, 0, 0);
        }
    };

    // ---- per-tap A read addresses (shorts within one As buffer), constant over K
    int addrA[9];
#pragma unroll
    for (int tap = 0; tap < 9; ++tap) {
        const int dt = (tap / 3 - 1) * ratio;
        const int dn = (tap % 3 - 1) * ratio;
        const bool tv = (unsigned)(t_w + dt) < (unsigned)Tt;   // wave-uniform
        const bool nv = (unsigned)(l15 + dn) < (unsigned)Nn;   // per-lane
        const int r  = wrow + l15 + 40 + dt * 16 + dn;         // window row
        const int rr = (tv && nv) ? r : 144;                   // else zero row
        addrA[tap] = rr * 32 + ((quad ^ (rr & 3)) << 3);
    }
    const int bOff0 = l15 * 32 + ((quad ^ (l15 & 3)) << 3);

    // zero row 144 in both buffers (staging never touches rows >= 144)
    if (tid < 8) {
        short8 z = {0, 0, 0, 0, 0, 0, 0, 0};
        *(short8*)&As[tid >> 2][144 * 32 + (tid & 3) * 8] = z;
    }

    floatx4 acc[2];
    acc[0] = (floatx4){0.f, 0.f, 0.f, 0.f};
    acc[1] = (floatx4){0.f, 0.f, 0.f, 0.f};

    stage(0, kc);
    __syncthreads();
    int cur = 0;
#pragma unroll
    for (int ks = 0; ks < 4; ++ks) {                // 4 K-steps of 32
        const bool more = (ks < 3);
        if (more) stage(cur ^ 1, kc + (ks + 1) * 32);   // prefetch under the MFMAs
#pragma unroll
        for (int tap = 0; tap < 9; ++tap) {
            const half8 av  = __builtin_bit_cast(half8, *(const short8*)&As[cur][addrA[tap]]);
            const half8 bv0 = __builtin_bit_cast(half8, *(const short8*)&Bs[cur][tap * 1024 + bOff0]);
            const half8 bv1 = __builtin_bit_cast(half8, *(const short8*)&Bs[cur][tap * 1024 + 512 + bOff0]);
            acc[0] = __builtin_amdgcn_mfma_f32_16x16x32_f16(av, bv0, acc[0], 0, 0, 0);
            acc[1] = __builtin_amdgcn_mfma_f32_16x16x32_f16(av, bv1, acc[1], 0, 0, 0);
        }
        if (more) __syncthreads();                  // single drain point per K-step
        cur ^= 1;
    }

    // partial K-sum -> atomic accumulate into bias-initialized off
#pragma unroll
    for (int j = 0; j < 2; ++j) {
        const int o = j * 16 + l15;
        if (o < 18) {
            const int grow = row0 + wrow + quad * 4;
#pragma unroll
            for (int r = 0; r < 4; ++r)
                atomicAdd(&off[(size_t)(grow + r) * 18 + o], acc[j][r]);
        }
    }
}

// ---------------------------------------------------------------------------
// Kernel 2: fused deformable bilinear gather, descriptor form (round-1 known-
// good config: fp32 pf reads, bijective XCD swizzle, nontemporal mad stores).
// ---------------------------------------------------------------------------
__global__ __launch_bounds__(256) void gather_kernel(const float* __restrict__ pf,
                                                     const float* __restrict__ off1,
                                                     const float* __restrict__ off2,
                                                     unsigned short* __restrict__ Ab,
                                                     float* __restrict__ mad) {
    const int bid = blockIdx.x;
    const int row = (bid & 7) * (ROWS / 8) + (bid >> 3);   // bijective XCD swizzle
    const int b = row / (Tt * Nn);
    const int t = (row / Nn) % Tt;
    const int n = row % Nn;
    const int tid = threadIdx.x;

    __shared__ float4 scoef[18];
    __shared__ int4   soffs[18];

    if (tid < 18) {
        const int ratio = (tid < 9) ? 1 : 2;
        const int k = (tid < 9) ? tid : tid - 9;
        const float* offarr = (tid < 9) ? off1 : off2;
        const float ot = offarr[(size_t)row * 18 + k];
        const float on = offarr[(size_t)row * 18 + 9 + k];
        const float tmax = (float)(Tt + 2 * ratio - 1);
        const float nmax = (float)(Nn + 2 * ratio - 1);
        const float pos_t = (float)(t + ratio + (k / 3 - 1) * ratio) + ot;
        const float pos_n = (float)(n + ratio + (k % 3 - 1) * ratio) + on;

        const float fl_t = floorf(pos_t), fl_n = floorf(pos_n);
        const float l_t = fminf(fmaxf(fl_t, 0.f), tmax);
        const float r_t = fminf(fmaxf(fl_t + 1.f, 0.f), tmax);
        const float l_n = fminf(fmaxf(fl_n, 0.f), nmax);
        const float r_n = fminf(fmaxf(fl_n + 1.f, 0.f), nmax);
        const float pt_ = fminf(fmaxf(pos_t, 0.f), tmax);
        const float pn_ = fminf(fmaxf(pos_n, 0.f), nmax);

        const float wtl = 1.f - fabsf(pt_ - l_t);
        const float wtr = 1.f - fabsf(pt_ - r_t);
        const float wnl = 1.f - fabsf(pn_ - l_n);
        const float wnr = 1.f - fabsf(pn_ - r_n);

        const int ilt = (int)l_t - ratio, irt = (int)r_t - ratio;
        const int iln = (int)l_n - ratio, irn = (int)r_n - ratio;
        const bool vtl = (unsigned)ilt < (unsigned)Tt;
        const bool vtr = (unsigned)irt < (unsigned)Tt;
        const bool vnl = (unsigned)iln < (unsigned)Nn;
        const bool vnr = (unsigned)irn < (unsigned)Nn;

        const int bb = b * Tt;
        float4 cf;
        int4 of;
        const bool g0 = vtl && vnl, g1 = vtr && vnr, g2 = vtr && vnl, g3 = vtl && vnr;
        cf.x = g0 ? wtl * wnl : 0.f;
        cf.y = g1 ? wtr * wnr : 0.f;
        cf.z = g2 ? wtr * wnl : 0.f;
        cf.w = g3 ? wtl * wnr : 0.f;
        of.x = g0 ? ((bb + ilt) * Nn + iln) * Cc : 0;
        of.y = g1 ? ((bb + irt) * Nn + irn) * Cc : 0;
        of.z = g2 ? ((bb + irt) * Nn + iln) * Cc : 0;
        of.w = g3 ? ((bb + ilt) * Nn + irn) * Cc : 0;
        scoef[tid] = cf;
        soffs[tid] = of;
    }
    __syncthreads();

    const int c4 = tid * 4;
    float ax = 0.f, ay = 0.f, az = 0.f, aw = 0.f;

#pragma unroll
    for (int d = 0; d < 9; ++d) {
        const float4 cf = scoef[d];
        const int4 of = soffs[d];
        const float4 v0 = *(const float4*)(pf + of.x + c4);
        const float4 v1 = *(const float4*)(pf + of.y + c4);
        const float4 v2 = *(const float4*)(pf + of.z + c4);
        const float4 v3 = *(const float4*)(pf + of.w + c4);
        ax += cf.x * v0.x + cf.y * v1.x + cf.z * v2.x + cf.w * v3.x;
        ay += cf.x * v0.y + cf.y * v1.y + cf.z * v2.y + cf.w * v3.y;
        az += cf.x * v0.z + cf.y * v1.z + cf.z * v2.z + cf.w * v3.z;
        aw += cf.x * v0.w + cf.y * v1.w + cf.z * v2.w + cf.w * v3.w;
    }
#pragma unroll
    for (int d = 9; d < 18; ++d) {
        const float4 cf = scoef[d];
        const int4 of = soffs[d];
        const float4 v0 = *(const float4*)(pf + of.x + c4);
        const float4 v1 = *(const float4*)(pf + of.y + c4);
        const float4 v2 = *(const float4*)(pf + of.z + c4);
        const float4 v3 = *(const float4*)(pf + of.w + c4);
        floatx4 val;
        val.x = cf.x * v0.x + cf.y * v1.x + cf.z * v2.x + cf.w * v3.x;
        val.y = cf.x * v0.y + cf.y * v1.y + cf.z * v2.y + cf.w * v3.y;
        val.z = cf.x * v0.z + cf.y * v1.z + cf.z * v2.z + cf.w * v3.z;
        val.w = cf.x * v0.w + cf.y * v1.w + cf.z * v2.w + cf.w * v3.w;
        __builtin_nontemporal_store(val,
            (floatx4*)(mad + ((size_t)row * 9 + (d - 9)) * Cc + c4));
        ax += val.x; ay += val.y; az += val.z; aw += val.w;
    }

    ushort4 o;
    o.x = f2bf(ax * (1.f / 18.f));
    o.y = f2bf(ay * (1.f / 18.f));
    o.z = f2bf(az * (1.f / 18.f));
    o.w = f2bf(aw * (1.f / 18.f));
    *(ushort4*)(Ab + (size_t)row * Cc + c4) = o;
}

// ---------------------------------------------------------------------------
// Kernel 3: bf16 MFMA GEMM  C[M][N] = A[M][K] * B[N][K]^T, 64x64 tiles
// (grid 40x16 = 640 blocks — round-1 known-good config). 4 waves, each 32x32.
// BK=64 double-buffered, single barrier per K-step. Nontemporal C stores.
// ---------------------------------------------------------------------------
__global__ __launch_bounds__(256) void gemm_bt_kernel(const unsigned short* __restrict__ A,
                                                      const unsigned short* __restrict__ Bw,
                                                      float* __restrict__ C,
                                                      int M, int N, int K) {
    __shared__ unsigned short As[2][64 * 64];   // 2 x 8 KB
    __shared__ unsigned short Bs[2][64 * 64];   // 2 x 8 KB

    const int tid  = threadIdx.x;
    const int lane = tid & 63;
    const int wave = tid >> 6;
    const int quad = lane >> 4;
    const int l15  = lane & 15;
    const int row0 = blockIdx.x * 64;
    const int col0 = blockIdx.y * 64;
    const int wm = (wave >> 1) * 32;
    const int wn = (wave & 1) * 32;

    floatx4 acc[2][2];
#pragma unroll
    for (int i = 0; i < 2; ++i)
#pragma unroll
        for (int j = 0; j < 2; ++j) acc[i][j] = (floatx4){0.f, 0.f, 0.f, 0.f};

    const int p  = tid & 7;
    const int m0 = tid >> 3;
    const int m1 = m0 + 32;
    const int kq0 = p ^ (m0 & 7);
    const int kq1 = p ^ (m1 & 7);

    const unsigned short* gA0 = A  + (size_t)(row0 + m0) * K + kq0 * 8;
    const unsigned short* gA1 = A  + (size_t)(row0 + m1) * K + kq1 * 8;
    const unsigned short* gB0 = Bw + (size_t)(col0 + m0) * K + kq0 * 8;
    const unsigned short* gB1 = Bw + (size_t)(col0 + m1) * K + kq1 * 8;

    auto stage = [&](int buf, int kt) {
        unsigned short* a  = &As[buf][0] + wave * 512;
        unsigned short* bb = &Bs[buf][0] + wave * 512;
        __builtin_amdgcn_global_load_lds((guint*)(const void*)(gA0 + kt),
                                         (luint*)(void*)a, 16, 0, 0);
        __builtin_amdgcn_global_load_lds((guint*)(const void*)(gA1 + kt),
                                         (luint*)(void*)(a + 2048), 16, 0, 0);
        __builtin_amdgcn_global_load_lds((guint*)(const void*)(gB0 + kt),
                                         (luint*)(void*)bb, 16, 0, 0);
        __builtin_amdgcn_global_load_lds((guint*)(const void*)(gB1 + kt),
                                         (luint*)(void*)(bb + 2048), 16, 0, 0);
    };

    stage(0, 0);
    __syncthreads();
    int cur = 0;
    for (int kt = 0; kt < K; kt += 64) {
        const bool more = (kt + 64 < K);
        if (more) stage(cur ^ 1, kt + 64);   // prefetch under the MFMAs

#pragma unroll
        for (int kt2 = 0; kt2 < 2; ++kt2) {
            short8 af[2], bf[2];
#pragma unroll
            for (int i = 0; i < 2; ++i) {
                const int mm = wm + i * 16 + l15;
                af[i] = *(const short8*)&As[cur][mm * 64 + (((kt2 * 4 + quad) ^ (mm & 7)) << 3)];
                const int nn = wn + i * 16 + l15;
                bf[i] = *(const short8*)&Bs[cur][nn * 64 + (((kt2 * 4 + quad) ^ (nn & 7)) << 3)];
            }
#pragma unroll
            for (int i = 0; i < 2; ++i)
#pragma unroll
                for (int j = 0; j < 2; ++j)
                    acc[i][j] = __builtin_amdgcn_mfma_f32_16x16x32_bf16(af[i], bf[j], acc[i][j], 0, 0, 0);
        }
        if (more) __syncthreads();
        cur ^= 1;
    }

#pragma unroll
    for (int i = 0; i < 2; ++i)
#pragma unroll
        for (int j = 0; j < 2; ++j)
#pragma unroll
            for (int r = 0; r < 4; ++r) {
                const int row = row0 + wm + i * 16 + quad * 4 + r;
                const int col = col0 + wn + j * 16 + l15;
                __builtin_nontemporal_store(acc[i][j][r], &C[(size_t)row * N + col]);
            }
}

// ---------------------------------------------------------------------------
extern "C" void kernel_launch(void* const* d_in, const int* in_sizes, int n_in,
                              void* d_out, int out_size, void* d_ws, size_t ws_size,
                              hipStream_t stream) {
    const float* pf = (const float*)d_in[0];   // [B,T,N,C]
    const float* Wh = (const float*)d_in[1];   // [C,C]
    const float* w1 = (const float*)d_in[2];   // [18,C,3,3]
    const float* b1 = (const float*)d_in[3];   // [18]
    const float* w2 = (const float*)d_in[4];
    const float* b2 = (const float*)d_in[5];

    float* dyn = (float*)d_out;                    // [ROWS][C]
    float* mad = dyn + (size_t)ROWS * Cc;          // [ROWS][9][C]

    // workspace layout
    float* off1  = (float*)d_ws;                                  // ROWS*18
    float* off2  = off1 + (size_t)ROWS * 18;                      // ROWS*18
    unsigned short* Ab = (unsigned short*)(off2 + (size_t)ROWS * 18);    // ROWS*C bf16
    unsigned short* Wb = Ab + (size_t)ROWS * Cc;                  // C*C bf16
    _Float16* xh  = (_Float16*)(Wb + (size_t)Cc * Cc);            // ROWS*C fp16
    _Float16* wh1 = xh + (size_t)ROWS * Cc;                       // 9*32*C fp16
    _Float16* wh2 = wh1 + (size_t)9 * 32 * Cc;                    // 9*32*C fp16

    prep_kernel<<<SEG3, 256, 0, stream>>>(pf, Wh, w1, b1, w2, b2,
                                          Wb, xh, wh1, wh2, off1, off2);
    offs_mfma_kernel<<<dim3(ROWS / 64, 8, 2), 256, 0, stream>>>(xh, wh1, wh2, off1, off2);
    gather_kernel<<<ROWS, 256, 0, stream>>>(pf, off1, off2, Ab, mad);
    gemm_bt_kernel<<<dim3(40, 16), 256, 0, stream>>>(Ab, Wb, dyn, ROWS, Cc, Cc);
}